// Round 32
// baseline (279.744 us; speedup 1.0000x reference)
//
#include <hip/hip_runtime.h>

#define N_NODES 100000
#define N_EDGES 3200000
#define F_IN    1433
#define HID     16
#define N_CLS   7
#define NWINT   48                                   // K windows of 32 (K padded to 1536)
#define GB1     (N_NODES / 4)                        // 25000 gemm strips of 4 rows (exact)
#define QBLK    (N_EDGES / 4 / 256)                  // 3125 fill blocks (exact quads)
#define NTOT    ((long)N_NODES * F_IN)               // 143,300,000
#define LSTR    1444                                 // LDS row stride (floats)
#define XSN     6144                                 // LDS floats (6 sweeps x 1024)
#define NBKT    1024                                 // buckets
#define NPBK    98                                   // nodes per bucket (1024*98=100352)
#define BCAP2   512                                  // cap per (xcd,bucket); mean 391 +6σ
#define SRCM    0x1FFFF                              // 17-bit src mask

typedef __attribute__((ext_vector_type(8))) short short8v;
typedef __attribute__((ext_vector_type(4))) float float4v;

typedef const __attribute__((address_space(1))) unsigned* gptr_t;
typedef __attribute__((address_space(3))) unsigned* lptr_t;

__device__ __forceinline__ unsigned short f2bf(float f) {
    unsigned u = __float_as_uint(f);
    u += 0x7fffu + ((u >> 16) & 1u);                 // RNE
    return (unsigned short)(u >> 16);
}

__device__ __forceinline__ void gll16(const float* g, float* lds) {
    gptr_t gp = (gptr_t)(unsigned long long)(uintptr_t)g;
    lptr_t lp = (lptr_t)(unsigned)(uintptr_t)lds;    // LDS addr fits 32 bits
    __builtin_amdgcn_global_load_lds(gp, lp, 16, 0, 0);
}

// ---------------- prep: pre-swizzled bf16 W1 fragments (zero past F_IN) -----
__global__ void prep_w1_kernel(const float* __restrict__ W1, short* __restrict__ w1f) {
    int w = blockIdx.x;
    int l = threadIdx.x;
    int col = l & 15;
    int kb = w * 32 + (l >> 4) * 8;
    short8v f;
#pragma unroll
    for (int i = 0; i < 8; ++i) {
        int k = kb + i;
        float v = (k < F_IN) ? W1[k * HID + col] : 0.f;
        f[i] = (short)f2bf(v);
    }
    *(short8v*)(w1f + ((size_t)w * 64 + l) * 8) = f;
}

// ---------------- gemm arm: 4-row strip, sequential 22.9KB stage ------------
// R32: halve R31's strip (8->4 rows) -> LDS 24.6KB -> 6 blocks/CU (was 3).
// The stage->drain->short-compute structure needs co-resident read streams
// for overlap (repack dynamics); doubling resident blocks doubles them.
// A-rows 4..15 are zero in the MFMA (util ~0.5%: free).
__device__ __noinline__ void gemm_arm(int gid, const float* __restrict__ x,
                                      const short* __restrict__ w1f,
                                      float* __restrict__ t1) {
    __shared__ float xs[XSN];              // 24.6KB: 4 rows x 1444 + slack
    const int tid = threadIdx.x;
    const int s = tid >> 6;                // wave / K-slice
    const int l = tid & 63;                // lane
    const int R0 = gid * 4;
    const int g = l >> 4;                  // k-group
    const int c = l & 15;                  // A row (valid <4) / B col

    short8v bf[12];                        // windows s*12 .. s*12+11
#pragma unroll
    for (int wl = 0; wl < 12; ++wl)
        bf[wl] = *(const short8v*)(w1f + ((size_t)((s * 12 + wl) * 64 + l)) * 8);

    if (gid != GB1 - 1) {
        // fast staging: 6 x 4KB sweeps, dest linear, per-lane de-pad source
#pragma unroll
        for (int j = 0; j < 6; ++j) {
            int df = j * 1024 + tid * 4;              // dest float idx
            unsigned row = (unsigned)df / (unsigned)LSTR;
            unsigned col = (unsigned)df - row * (unsigned)LSTR;
            long src = (row < 4 && col < 1433)
                           ? (long)(R0 + (int)row) * F_IN + col
                           : 0;                        // dead slot: safe addr
            gll16(x + src, &xs[df]);
        }
        __syncthreads();
    } else {
        // last strip: exact-guarded scalar staging (no 16B overrun past x)
        for (int idx = tid; idx < 4 * LSTR; idx += 256) {
            int row = idx / LSTR, col = idx - row * LSTR;
            float v = (col < F_IN) ? x[(long)(R0 + row) * F_IN + col] : 0.f;
            xs[idx] = v;
        }
        for (int idx = 4 * LSTR + tid; idx < XSN; idx += 256) xs[idx] = 0.f;
        __syncthreads();
    }

    const int kb = s * 384;                // wave K base
    const bool act = (c < 4);
    float4v acc = {0.f, 0.f, 0.f, 0.f};
#pragma unroll
    for (int wl = 0; wl < 12; ++wl) {
        int off = c * LSTR + kb + wl * 32 + g * 8;    // c<4 only
        float4 lo = {0.f, 0.f, 0.f, 0.f}, hi = {0.f, 0.f, 0.f, 0.f};
        if (act) {
            lo = *(const float4*)(&xs[off]);
            hi = *(const float4*)(&xs[off + 4]);
        }
        short8v af;
        af[0] = (short)f2bf(lo.x); af[1] = (short)f2bf(lo.y);
        af[2] = (short)f2bf(lo.z); af[3] = (short)f2bf(lo.w);
        af[4] = (short)f2bf(hi.x); af[5] = (short)f2bf(hi.y);
        af[6] = (short)f2bf(hi.z); af[7] = (short)f2bf(hi.w);
        acc = __builtin_amdgcn_mfma_f32_16x16x32_bf16(af, bf[wl], acc, 0, 0, 0);
    }

    // cross-wave K reduction (reuse xs; rows 0..3 live in lanes 0..15, j=r)
    __syncthreads();
    float* reds = &xs[s * 256];
#pragma unroll
    for (int j = 0; j < 4; ++j) reds[l * 4 + j] = acc[j];
    __syncthreads();
    if (tid < 64) {
        int r = tid >> 4, cc = tid & 15;   // r 0..3
        int idx = cc * 4 + r;              // ((r>>2)=0)*16+cc)*4 + (r&3)
        float vv = xs[idx] + xs[256 + idx] + xs[512 + idx] + xs[768 + idx];
        t1[(long)(R0 + r) * HID + cc] = vv;
    }
}

// ---------------- fill arm (noinline): XCD-private 8x1024 buckets -----------
__device__ __noinline__ void fill_arm(int fbid, const int* __restrict__ src,
                                      const int* __restrict__ dst,
                                      int* __restrict__ cnt, int* __restrict__ bkt) {
    const int p = blockIdx.x & 7;                    // blockIdx->XCD round-robin
    int i = fbid * 256 + threadIdx.x;                // exact: 3125*256 = 800k quads
    int4 s4 = ((const int4*)src)[i];
    int4 d4 = ((const int4*)dst)[i];
    unsigned b, dl; int pos;
    b = (unsigned)d4.x / NPBK; dl = (unsigned)d4.x - b * NPBK;
    pos = atomicAdd(&cnt[(p << 10) + b], 1);
    if (pos < BCAP2) bkt[((size_t)((p << 10) + b) << 9) + pos] = (int)((dl << 17) | (unsigned)s4.x);
    b = (unsigned)d4.y / NPBK; dl = (unsigned)d4.y - b * NPBK;
    pos = atomicAdd(&cnt[(p << 10) + b], 1);
    if (pos < BCAP2) bkt[((size_t)((p << 10) + b) << 9) + pos] = (int)((dl << 17) | (unsigned)s4.y);
    b = (unsigned)d4.z / NPBK; dl = (unsigned)d4.z - b * NPBK;
    pos = atomicAdd(&cnt[(p << 10) + b], 1);
    if (pos < BCAP2) bkt[((size_t)((p << 10) + b) << 9) + pos] = (int)((dl << 17) | (unsigned)s4.z);
    b = (unsigned)d4.w / NPBK; dl = (unsigned)d4.w - b * NPBK;
    pos = atomicAdd(&cnt[(p << 10) + b], 1);
    if (pos < BCAP2) bkt[((size_t)((p << 10) + b) << 9) + pos] = (int)((dl << 17) | (unsigned)s4.w);
}

// ---------------- fat1: gemm ++ fill INTERLEAVED 8:1 ------------------------
// Grid = 28125 = 3125*9 exactly: bid%9==8 -> fill, else gemm (gid=bid-bid/9).
__global__ __launch_bounds__(256) void fat1_kernel(const float* __restrict__ x,
                                                   const short* __restrict__ w1f,
                                                   float* __restrict__ t1,
                                                   const int* __restrict__ src,
                                                   const int* __restrict__ dst,
                                                   int* __restrict__ cnt,
                                                   int* __restrict__ bkt) {
    const int bid = blockIdx.x;
    if (bid % 9 == 8) fill_arm(bid / 9, src, dst, cnt, bkt);
    else              gemm_arm(bid - bid / 9, x, w1f, t1);
}

// ---------------- agg1 + fused gemm2: LDS-CSR node-centric (R30-verbatim) ---
__global__ __launch_bounds__(256) void agg1f_kernel(const float* __restrict__ t1,
                                                    const int* __restrict__ cnt,
                                                    const int* __restrict__ bkt,
                                                    const float* __restrict__ b1,
                                                    const float* __restrict__ W2,
                                                    float* __restrict__ t2p) {
    __shared__ int els[4096];
    __shared__ int ecsr[4096];
    __shared__ int dcnt[128], doff[128], dcur[128];
    __shared__ int pbase[9];
    __shared__ float hl[NPBK][16];
    const int b = blockIdx.x;
    const int t = threadIdx.x;
    if (t == 0) {
        int s = 0;
        for (int p = 0; p < 8; ++p) {
            pbase[p] = s;
            int ne = cnt[(p << 10) + b]; if (ne > BCAP2) ne = BCAP2;
            s += ne;
        }
        pbase[8] = s;
    }
    if (t < 128) dcnt[t] = 0;
    __syncthreads();
    const int nt = pbase[8];
    for (int p = 0; p < 8; ++p) {
        int base0 = pbase[p], ne = pbase[p + 1] - base0;
        const int* __restrict__ bp = bkt + ((size_t)((p << 10) + b) << 9);
        for (int e = t; e < ne; e += 256) els[base0 + e] = bp[e];
    }
    __syncthreads();
    for (int e = t; e < nt; e += 256) atomicAdd(&dcnt[els[e] >> 17], 1);
    __syncthreads();
    if (t < 128) doff[t] = dcnt[t];
    __syncthreads();
    for (int d = 1; d < 128; d <<= 1) {
        int add = (t < 128 && t >= d) ? doff[t - d] : 0;
        __syncthreads();
        if (t < 128) doff[t] += add;
        __syncthreads();
    }
    if (t < 128) dcur[t] = doff[t] - dcnt[t];        // exclusive offsets
    __syncthreads();
    for (int e = t; e < nt; e += 256) {
        int v = els[e];
        int pos = atomicAdd(&dcur[v >> 17], 1);
        ecsr[pos] = v & SRCM;
    }
    __syncthreads();
    const int nbase = b * NPBK;
    {
        int q = t & 3;
        for (int nl = t >> 2; nl < NPBK; nl += 64) {
            int node = nbase + nl;
            if (node < N_NODES) {
                int o = doff[nl] - dcnt[nl];
                int d = dcnt[nl];
                float4 a0 = *(const float4*)(t1 + ((size_t)node * 16 + q * 4));
                float4 bb = *(const float4*)(b1 + q * 4);
                a0.x += bb.x; a0.y += bb.y; a0.z += bb.z; a0.w += bb.w;
                float4 a1 = {0.f, 0.f, 0.f, 0.f};
                int e = 0;
                for (; e + 4 <= d; e += 4) {          // 4 gathers in flight
                    int s0 = ecsr[o + e],     s1 = ecsr[o + e + 1];
                    int s2 = ecsr[o + e + 2], s3 = ecsr[o + e + 3];
                    float4 v0 = *(const float4*)(t1 + ((size_t)s0 * 16 + q * 4));
                    float4 v1 = *(const float4*)(t1 + ((size_t)s1 * 16 + q * 4));
                    float4 v2 = *(const float4*)(t1 + ((size_t)s2 * 16 + q * 4));
                    float4 v3 = *(const float4*)(t1 + ((size_t)s3 * 16 + q * 4));
                    a0.x += v0.x; a0.y += v0.y; a0.z += v0.z; a0.w += v0.w;
                    a1.x += v1.x; a1.y += v1.y; a1.z += v1.z; a1.w += v1.w;
                    a0.x += v2.x; a0.y += v2.y; a0.z += v2.z; a0.w += v2.w;
                    a1.x += v3.x; a1.y += v3.y; a1.z += v3.z; a1.w += v3.w;
                }
                for (; e < d; ++e) {
                    int s = ecsr[o + e];
                    float4 v = *(const float4*)(t1 + ((size_t)s * 16 + q * 4));
                    a0.x += v.x; a0.y += v.y; a0.z += v.z; a0.w += v.w;
                }
                float4 r = {fmaxf(a0.x + a1.x, 0.f), fmaxf(a0.y + a1.y, 0.f),
                            fmaxf(a0.z + a1.z, 0.f), fmaxf(a0.w + a1.w, 0.f)};
                *(float4*)(&hl[nl][q * 4]) = r;
            }
        }
    }
    __syncthreads();
    for (int idx = t; idx < NPBK * 8; idx += 256) {
        int ln = idx >> 3, c = idx & 7;
        int node = nbase + ln;
        if (node < N_NODES) {
            float a = 0.f;
            if (c < N_CLS) {
#pragma unroll
                for (int j = 0; j < HID; ++j) a = fmaf(hl[ln][j], W2[j * N_CLS + c], a);
            }
            t2p[(size_t)node * 8 + c] = a;
        }
    }
}

// ---------------- agg2: LDS-CSR node-centric (R30-verbatim) -----------------
__global__ __launch_bounds__(256) void agg2_kernel(const float* __restrict__ t2p,
                                                   const int* __restrict__ cnt,
                                                   const int* __restrict__ bkt,
                                                   const float* __restrict__ b2,
                                                   float* __restrict__ out) {
    __shared__ int els[4096];
    __shared__ int ecsr[4096];
    __shared__ int dcnt[128], doff[128], dcur[128];
    __shared__ int pbase[9];
    const int b = blockIdx.x;
    const int t = threadIdx.x;
    if (t == 0) {
        int s = 0;
        for (int p = 0; p < 8; ++p) {
            pbase[p] = s;
            int ne = cnt[(p << 10) + b]; if (ne > BCAP2) ne = BCAP2;
            s += ne;
        }
        pbase[8] = s;
    }
    if (t < 128) dcnt[t] = 0;
    __syncthreads();
    const int nt = pbase[8];
    for (int p = 0; p < 8; ++p) {
        int base0 = pbase[p], ne = pbase[p + 1] - base0;
        const int* __restrict__ bp = bkt + ((size_t)((p << 10) + b) << 9);
        for (int e = t; e < ne; e += 256) els[base0 + e] = bp[e];
    }
    __syncthreads();
    for (int e = t; e < nt; e += 256) atomicAdd(&dcnt[els[e] >> 17], 1);
    __syncthreads();
    if (t < 128) doff[t] = dcnt[t];
    __syncthreads();
    for (int d = 1; d < 128; d <<= 1) {
        int add = (t < 128 && t >= d) ? doff[t - d] : 0;
        __syncthreads();
        if (t < 128) doff[t] += add;
        __syncthreads();
    }
    if (t < 128) dcur[t] = doff[t] - dcnt[t];
    __syncthreads();
    for (int e = t; e < nt; e += 256) {
        int v = els[e];
        int pos = atomicAdd(&dcur[v >> 17], 1);
        ecsr[pos] = v & SRCM;
    }
    __syncthreads();
    const int nbase = b * NPBK;
    {
        int q = t & 1;
        for (int nl = t >> 1; nl < NPBK; nl += 128) {
            int node = nbase + nl;
            if (node < N_NODES) {
                int o = doff[nl] - dcnt[nl];
                int d = dcnt[nl];
                float4 a0 = *(const float4*)(t2p + ((size_t)node * 8 + q * 4));
                if (q == 0) {
                    a0.x += b2[0]; a0.y += b2[1]; a0.z += b2[2]; a0.w += b2[3];
                } else {
                    a0.x += b2[4]; a0.y += b2[5]; a0.z += b2[6];
                }
                float4 a1 = {0.f, 0.f, 0.f, 0.f};
                int e = 0;
                for (; e + 4 <= d; e += 4) {          // 4 gathers in flight
                    int s0 = ecsr[o + e],     s1 = ecsr[o + e + 1];
                    int s2 = ecsr[o + e + 2], s3 = ecsr[o + e + 3];
                    float4 v0 = *(const float4*)(t2p + ((size_t)s0 * 8 + q * 4));
                    float4 v1 = *(const float4*)(t2p + ((size_t)s1 * 8 + q * 4));
                    float4 v2 = *(const float4*)(t2p + ((size_t)s2 * 8 + q * 4));
                    float4 v3 = *(const float4*)(t2p + ((size_t)s3 * 8 + q * 4));
                    a0.x += v0.x; a0.y += v0.y; a0.z += v0.z; a0.w += v0.w;
                    a1.x += v1.x; a1.y += v1.y; a1.z += v1.z; a1.w += v1.w;
                    a0.x += v2.x; a0.y += v2.y; a0.z += v2.z; a0.w += v2.w;
                    a1.x += v3.x; a1.y += v3.y; a1.z += v3.z; a1.w += v3.w;
                }
                for (; e < d; ++e) {
                    int s = ecsr[o + e];
                    float4 v = *(const float4*)(t2p + ((size_t)s * 8 + q * 4));
                    a0.x += v.x; a0.y += v.y; a0.z += v.z; a0.w += v.w;
                }
                float* op = out + (size_t)node * 7 + q * 4;
                op[0] = a0.x + a1.x; op[1] = a0.y + a1.y; op[2] = a0.z + a1.z;
                if (q == 0) op[3] = a0.w + a1.w;
            }
        }
    }
}

// ---------------- launch ----------------

extern "C" void kernel_launch(void* const* d_in, const int* in_sizes, int n_in,
                              void* d_out, int out_size, void* d_ws, size_t ws_size,
                              hipStream_t stream) {
    const float* x  = (const float*)d_in[0];
    const int*   ei = (const int*)d_in[1];
    const float* W1 = (const float*)d_in[2];
    const float* b1 = (const float*)d_in[3];
    const float* W2 = (const float*)d_in[4];
    const float* b2 = (const float*)d_in[5];
    const int* src = ei;
    const int* dst = ei + N_EDGES;
    float* out = (float*)d_out;

    char* w = (char*)d_ws;
    float* t1  = (float*)w;  w += (size_t)N_NODES * HID * sizeof(float);
    float* t2p = (float*)w;  w += (size_t)N_NODES * 8 * sizeof(float);
    short* w1f = (short*)w;  w += (size_t)NWINT * 64 * 8 * sizeof(short);
    int* cnt   = (int*)w;    w += (size_t)8 * NBKT * sizeof(int);
    int* bkt   = (int*)w;    w += (size_t)8 * NBKT * BCAP2 * sizeof(int);

    (void)hipMemsetAsync(cnt, 0, (size_t)8 * NBKT * sizeof(int), stream);
    prep_w1_kernel<<<NWINT, 64, 0, stream>>>(W1, w1f);

    // gemm (4-row sequential strips, 6 blk/CU) ++ fill interleaved 8:1
    fat1_kernel<<<GB1 + QBLK, 256, 0, stream>>>(x, w1f, t1, src, dst, cnt, bkt);

    agg1f_kernel<<<NBKT, 256, 0, stream>>>(t1, cnt, bkt, b1, W2, t2p);
    agg2_kernel<<<NBKT, 256, 0, stream>>>(t2p, cnt, bkt, b2, out);
}

// Round 33
// 270.847 us; speedup vs baseline: 1.0328x; 1.0328x over previous
//
#include <hip/hip_runtime.h>

#define N_NODES 100000
#define N_EDGES 3200000
#define F_IN    1433
#define HID     16
#define N_CLS   7
#define NWINT   48                                   // K windows of 32 (K padded to 1536)
#define GB1     (N_NODES / 8)                        // 12500 gemm strips of 8 rows (exact)
#define QBLK    (N_EDGES / 4 / 256)                  // 3125 fill blocks (exact quads)
#define NTOT    ((long)N_NODES * F_IN)               // 143,300,000
#define LSTR    1444                                 // LDS row stride (floats)
#define NBKT    1024                                 // buckets
#define NPBK    98                                   // nodes per bucket (1024*98=100352)
#define BCAP2   512                                  // cap per (xcd,bucket); mean 391 +6σ
#define SRCM    0x1FFFF                              // 17-bit src mask

typedef __attribute__((ext_vector_type(8))) short short8v;
typedef __attribute__((ext_vector_type(4))) float float4v;

typedef const __attribute__((address_space(1))) unsigned* gptr_t;
typedef __attribute__((address_space(3))) unsigned* lptr_t;

__device__ __forceinline__ unsigned short f2bf(float f) {
    unsigned u = __float_as_uint(f);
    u += 0x7fffu + ((u >> 16) & 1u);                 // RNE
    return (unsigned short)(u >> 16);
}

__device__ __forceinline__ void gll16(const float* g, float* lds) {
    gptr_t gp = (gptr_t)(unsigned long long)(uintptr_t)g;
    lptr_t lp = (lptr_t)(unsigned)(uintptr_t)lds;    // LDS addr fits 32 bits
    __builtin_amdgcn_global_load_lds(gp, lp, 16, 0, 0);
}

// ---------------- prep: pre-swizzled bf16 W1 fragments (zero past F_IN) -----
__global__ void prep_w1_kernel(const float* __restrict__ W1, short* __restrict__ w1f) {
    int w = blockIdx.x;
    int l = threadIdx.x;
    int col = l & 15;
    int kb = w * 32 + (l >> 4) * 8;
    short8v f;
#pragma unroll
    for (int i = 0; i < 8; ++i) {
        int k = kb + i;
        float v = (k < F_IN) ? W1[k * HID + col] : 0.f;
        f[i] = (short)f2bf(v);
    }
    *(short8v*)(w1f + ((size_t)w * 64 + l) * 8) = f;
}

// ---------------- gemm arm: 8-row strip, SEQUENTIAL 45.9KB stage ------------
// R31-verbatim (best measured: 270.8us total). Block = 8 adjacent rows = one
// contiguous 45,856B span of x; 12 x 4KB linear sweeps into LDS (stride-1444
// rows, per-lane de-pad source). MFMA A-rows 8..15 zero (free at 0.5% util).
__device__ __noinline__ void gemm_arm(int gid, const float* __restrict__ x,
                                      const short* __restrict__ w1f,
                                      float* __restrict__ t1) {
    __shared__ float xs[12288];            // 48KB: 8 rows x 1444 + sweep slack
    const int tid = threadIdx.x;
    const int s = tid >> 6;                // wave / K-slice
    const int l = tid & 63;                // lane
    const int R0 = gid * 8;
    const int g = l >> 4;                  // k-group
    const int c = l & 15;                  // A row (valid <8) / B col

    short8v bf[12];                        // windows s*12 .. s*12+11
#pragma unroll
    for (int wl = 0; wl < 12; ++wl)
        bf[wl] = *(const short8v*)(w1f + ((size_t)((s * 12 + wl) * 64 + l)) * 8);

    if (gid != GB1 - 1) {
        // fast staging: 12 x 4KB sweeps, dest linear, per-lane de-pad source
#pragma unroll
        for (int j = 0; j < 12; ++j) {
            int df = j * 1024 + tid * 4;              // dest float idx
            unsigned row = (unsigned)df / (unsigned)LSTR;
            unsigned col = (unsigned)df - row * (unsigned)LSTR;
            long src = (row < 8 && col < 1433)
                           ? (long)(R0 + (int)row) * F_IN + col
                           : 0;                        // dead slot: safe addr
            gll16(x + src, &xs[df]);
        }
        __syncthreads();
    } else {
        // last strip: exact-guarded scalar staging (no 16B overrun past x)
        for (int idx = tid; idx < 8 * LSTR; idx += 256) {
            int row = idx / LSTR, col = idx - row * LSTR;
            float v = (col < F_IN) ? x[(long)(R0 + row) * F_IN + col] : 0.f;
            xs[idx] = v;
        }
        for (int idx = 8 * LSTR + tid; idx < 12288; idx += 256) xs[idx] = 0.f;
        __syncthreads();
    }

    const int kb = s * 384;                // wave K base
    const bool act = (c < 8);
    float4v acc = {0.f, 0.f, 0.f, 0.f};
#pragma unroll
    for (int wl = 0; wl < 12; ++wl) {
        int off = c * LSTR + kb + wl * 32 + g * 8;    // c<8 only
        float4 lo = {0.f, 0.f, 0.f, 0.f}, hi = {0.f, 0.f, 0.f, 0.f};
        if (act) {
            lo = *(const float4*)(&xs[off]);
            hi = *(const float4*)(&xs[off + 4]);
        }
        short8v af;
        af[0] = (short)f2bf(lo.x); af[1] = (short)f2bf(lo.y);
        af[2] = (short)f2bf(lo.z); af[3] = (short)f2bf(lo.w);
        af[4] = (short)f2bf(hi.x); af[5] = (short)f2bf(hi.y);
        af[6] = (short)f2bf(hi.z); af[7] = (short)f2bf(hi.w);
        acc = __builtin_amdgcn_mfma_f32_16x16x32_bf16(af, bf[wl], acc, 0, 0, 0);
    }

    // cross-wave K reduction (reuse xs; D rows 8..15 are zero, ignored)
    __syncthreads();
    float* reds = &xs[s * 256];
#pragma unroll
    for (int j = 0; j < 4; ++j) reds[l * 4 + j] = acc[j];
    __syncthreads();
    if (tid < 128) {
        int r = tid >> 4, cc = tid & 15;   // r 0..7
        int idx = ((r >> 2) * 16 + cc) * 4 + (r & 3);
        float vv = xs[idx] + xs[256 + idx] + xs[512 + idx] + xs[768 + idx];
        t1[(long)(R0 + r) * HID + cc] = vv;
    }
}

// ---------------- fill arm (noinline): XCD-private 8x1024 buckets -----------
__device__ __noinline__ void fill_arm(int fbid, const int* __restrict__ src,
                                      const int* __restrict__ dst,
                                      int* __restrict__ cnt, int* __restrict__ bkt) {
    const int p = blockIdx.x & 7;                    // blockIdx->XCD round-robin
    int i = fbid * 256 + threadIdx.x;                // exact: 3125*256 = 800k quads
    int4 s4 = ((const int4*)src)[i];
    int4 d4 = ((const int4*)dst)[i];
    unsigned b, dl; int pos;
    b = (unsigned)d4.x / NPBK; dl = (unsigned)d4.x - b * NPBK;
    pos = atomicAdd(&cnt[(p << 10) + b], 1);
    if (pos < BCAP2) bkt[((size_t)((p << 10) + b) << 9) + pos] = (int)((dl << 17) | (unsigned)s4.x);
    b = (unsigned)d4.y / NPBK; dl = (unsigned)d4.y - b * NPBK;
    pos = atomicAdd(&cnt[(p << 10) + b], 1);
    if (pos < BCAP2) bkt[((size_t)((p << 10) + b) << 9) + pos] = (int)((dl << 17) | (unsigned)s4.y);
    b = (unsigned)d4.z / NPBK; dl = (unsigned)d4.z - b * NPBK;
    pos = atomicAdd(&cnt[(p << 10) + b], 1);
    if (pos < BCAP2) bkt[((size_t)((p << 10) + b) << 9) + pos] = (int)((dl << 17) | (unsigned)s4.z);
    b = (unsigned)d4.w / NPBK; dl = (unsigned)d4.w - b * NPBK;
    pos = atomicAdd(&cnt[(p << 10) + b], 1);
    if (pos < BCAP2) bkt[((size_t)((p << 10) + b) << 9) + pos] = (int)((dl << 17) | (unsigned)s4.w);
}

// ---------------- fat1: gemm ++ fill INTERLEAVED 4:1 ------------------------
// Grid = GB1 + QBLK = 15625. bid%5==4 -> fill (gcd(5,8)=1: all XCDs cycled).
__global__ __launch_bounds__(256) void fat1_kernel(const float* __restrict__ x,
                                                   const short* __restrict__ w1f,
                                                   float* __restrict__ t1,
                                                   const int* __restrict__ src,
                                                   const int* __restrict__ dst,
                                                   int* __restrict__ cnt,
                                                   int* __restrict__ bkt) {
    const int bid = blockIdx.x;
    if (bid % 5 == 4) fill_arm((bid - 4) / 5, src, dst, cnt, bkt);
    else              gemm_arm(bid - (bid + 1) / 5, x, w1f, t1);
}

// ---------------- agg1 + fused gemm2: LDS-CSR node-centric (R30-verbatim) ---
__global__ __launch_bounds__(256) void agg1f_kernel(const float* __restrict__ t1,
                                                    const int* __restrict__ cnt,
                                                    const int* __restrict__ bkt,
                                                    const float* __restrict__ b1,
                                                    const float* __restrict__ W2,
                                                    float* __restrict__ t2p) {
    __shared__ int els[4096];
    __shared__ int ecsr[4096];
    __shared__ int dcnt[128], doff[128], dcur[128];
    __shared__ int pbase[9];
    __shared__ float hl[NPBK][16];
    const int b = blockIdx.x;
    const int t = threadIdx.x;
    if (t == 0) {
        int s = 0;
        for (int p = 0; p < 8; ++p) {
            pbase[p] = s;
            int ne = cnt[(p << 10) + b]; if (ne > BCAP2) ne = BCAP2;
            s += ne;
        }
        pbase[8] = s;
    }
    if (t < 128) dcnt[t] = 0;
    __syncthreads();
    const int nt = pbase[8];
    for (int p = 0; p < 8; ++p) {
        int base0 = pbase[p], ne = pbase[p + 1] - base0;
        const int* __restrict__ bp = bkt + ((size_t)((p << 10) + b) << 9);
        for (int e = t; e < ne; e += 256) els[base0 + e] = bp[e];
    }
    __syncthreads();
    for (int e = t; e < nt; e += 256) atomicAdd(&dcnt[els[e] >> 17], 1);
    __syncthreads();
    if (t < 128) doff[t] = dcnt[t];
    __syncthreads();
    for (int d = 1; d < 128; d <<= 1) {
        int add = (t < 128 && t >= d) ? doff[t - d] : 0;
        __syncthreads();
        if (t < 128) doff[t] += add;
        __syncthreads();
    }
    if (t < 128) dcur[t] = doff[t] - dcnt[t];        // exclusive offsets
    __syncthreads();
    for (int e = t; e < nt; e += 256) {
        int v = els[e];
        int pos = atomicAdd(&dcur[v >> 17], 1);
        ecsr[pos] = v & SRCM;
    }
    __syncthreads();
    const int nbase = b * NPBK;
    {
        int q = t & 3;
        for (int nl = t >> 2; nl < NPBK; nl += 64) {
            int node = nbase + nl;
            if (node < N_NODES) {
                int o = doff[nl] - dcnt[nl];
                int d = dcnt[nl];
                float4 a0 = *(const float4*)(t1 + ((size_t)node * 16 + q * 4));
                float4 bb = *(const float4*)(b1 + q * 4);
                a0.x += bb.x; a0.y += bb.y; a0.z += bb.z; a0.w += bb.w;
                float4 a1 = {0.f, 0.f, 0.f, 0.f};
                int e = 0;
                for (; e + 4 <= d; e += 4) {          // 4 gathers in flight
                    int s0 = ecsr[o + e],     s1 = ecsr[o + e + 1];
                    int s2 = ecsr[o + e + 2], s3 = ecsr[o + e + 3];
                    float4 v0 = *(const float4*)(t1 + ((size_t)s0 * 16 + q * 4));
                    float4 v1 = *(const float4*)(t1 + ((size_t)s1 * 16 + q * 4));
                    float4 v2 = *(const float4*)(t1 + ((size_t)s2 * 16 + q * 4));
                    float4 v3 = *(const float4*)(t1 + ((size_t)s3 * 16 + q * 4));
                    a0.x += v0.x; a0.y += v0.y; a0.z += v0.z; a0.w += v0.w;
                    a1.x += v1.x; a1.y += v1.y; a1.z += v1.z; a1.w += v1.w;
                    a0.x += v2.x; a0.y += v2.y; a0.z += v2.z; a0.w += v2.w;
                    a1.x += v3.x; a1.y += v3.y; a1.z += v3.z; a1.w += v3.w;
                }
                for (; e < d; ++e) {
                    int s = ecsr[o + e];
                    float4 v = *(const float4*)(t1 + ((size_t)s * 16 + q * 4));
                    a0.x += v.x; a0.y += v.y; a0.z += v.z; a0.w += v.w;
                }
                float4 r = {fmaxf(a0.x + a1.x, 0.f), fmaxf(a0.y + a1.y, 0.f),
                            fmaxf(a0.z + a1.z, 0.f), fmaxf(a0.w + a1.w, 0.f)};
                *(float4*)(&hl[nl][q * 4]) = r;
            }
        }
    }
    __syncthreads();
    for (int idx = t; idx < NPBK * 8; idx += 256) {
        int ln = idx >> 3, c = idx & 7;
        int node = nbase + ln;
        if (node < N_NODES) {
            float a = 0.f;
            if (c < N_CLS) {
#pragma unroll
                for (int j = 0; j < HID; ++j) a = fmaf(hl[ln][j], W2[j * N_CLS + c], a);
            }
            t2p[(size_t)node * 8 + c] = a;
        }
    }
}

// ---------------- agg2: LDS-CSR node-centric (R30-verbatim) -----------------
__global__ __launch_bounds__(256) void agg2_kernel(const float* __restrict__ t2p,
                                                   const int* __restrict__ cnt,
                                                   const int* __restrict__ bkt,
                                                   const float* __restrict__ b2,
                                                   float* __restrict__ out) {
    __shared__ int els[4096];
    __shared__ int ecsr[4096];
    __shared__ int dcnt[128], doff[128], dcur[128];
    __shared__ int pbase[9];
    const int b = blockIdx.x;
    const int t = threadIdx.x;
    if (t == 0) {
        int s = 0;
        for (int p = 0; p < 8; ++p) {
            pbase[p] = s;
            int ne = cnt[(p << 10) + b]; if (ne > BCAP2) ne = BCAP2;
            s += ne;
        }
        pbase[8] = s;
    }
    if (t < 128) dcnt[t] = 0;
    __syncthreads();
    const int nt = pbase[8];
    for (int p = 0; p < 8; ++p) {
        int base0 = pbase[p], ne = pbase[p + 1] - base0;
        const int* __restrict__ bp = bkt + ((size_t)((p << 10) + b) << 9);
        for (int e = t; e < ne; e += 256) els[base0 + e] = bp[e];
    }
    __syncthreads();
    for (int e = t; e < nt; e += 256) atomicAdd(&dcnt[els[e] >> 17], 1);
    __syncthreads();
    if (t < 128) doff[t] = dcnt[t];
    __syncthreads();
    for (int d = 1; d < 128; d <<= 1) {
        int add = (t < 128 && t >= d) ? doff[t - d] : 0;
        __syncthreads();
        if (t < 128) doff[t] += add;
        __syncthreads();
    }
    if (t < 128) dcur[t] = doff[t] - dcnt[t];
    __syncthreads();
    for (int e = t; e < nt; e += 256) {
        int v = els[e];
        int pos = atomicAdd(&dcur[v >> 17], 1);
        ecsr[pos] = v & SRCM;
    }
    __syncthreads();
    const int nbase = b * NPBK;
    {
        int q = t & 1;
        for (int nl = t >> 1; nl < NPBK; nl += 128) {
            int node = nbase + nl;
            if (node < N_NODES) {
                int o = doff[nl] - dcnt[nl];
                int d = dcnt[nl];
                float4 a0 = *(const float4*)(t2p + ((size_t)node * 8 + q * 4));
                if (q == 0) {
                    a0.x += b2[0]; a0.y += b2[1]; a0.z += b2[2]; a0.w += b2[3];
                } else {
                    a0.x += b2[4]; a0.y += b2[5]; a0.z += b2[6];
                }
                float4 a1 = {0.f, 0.f, 0.f, 0.f};
                int e = 0;
                for (; e + 4 <= d; e += 4) {          // 4 gathers in flight
                    int s0 = ecsr[o + e],     s1 = ecsr[o + e + 1];
                    int s2 = ecsr[o + e + 2], s3 = ecsr[o + e + 3];
                    float4 v0 = *(const float4*)(t2p + ((size_t)s0 * 8 + q * 4));
                    float4 v1 = *(const float4*)(t2p + ((size_t)s1 * 8 + q * 4));
                    float4 v2 = *(const float4*)(t2p + ((size_t)s2 * 8 + q * 4));
                    float4 v3 = *(const float4*)(t2p + ((size_t)s3 * 8 + q * 4));
                    a0.x += v0.x; a0.y += v0.y; a0.z += v0.z; a0.w += v0.w;
                    a1.x += v1.x; a1.y += v1.y; a1.z += v1.z; a1.w += v1.w;
                    a0.x += v2.x; a0.y += v2.y; a0.z += v2.z; a0.w += v2.w;
                    a1.x += v3.x; a1.y += v3.y; a1.z += v3.z; a1.w += v3.w;
                }
                for (; e < d; ++e) {
                    int s = ecsr[o + e];
                    float4 v = *(const float4*)(t2p + ((size_t)s * 8 + q * 4));
                    a0.x += v.x; a0.y += v.y; a0.z += v.z; a0.w += v.w;
                }
                float* op = out + (size_t)node * 7 + q * 4;
                op[0] = a0.x + a1.x; op[1] = a0.y + a1.y; op[2] = a0.z + a1.z;
                if (q == 0) op[3] = a0.w + a1.w;
            }
        }
    }
}

// ---------------- launch ----------------

extern "C" void kernel_launch(void* const* d_in, const int* in_sizes, int n_in,
                              void* d_out, int out_size, void* d_ws, size_t ws_size,
                              hipStream_t stream) {
    const float* x  = (const float*)d_in[0];
    const int*   ei = (const int*)d_in[1];
    const float* W1 = (const float*)d_in[2];
    const float* b1 = (const float*)d_in[3];
    const float* W2 = (const float*)d_in[4];
    const float* b2 = (const float*)d_in[5];
    const int* src = ei;
    const int* dst = ei + N_EDGES;
    float* out = (float*)d_out;

    char* w = (char*)d_ws;
    float* t1  = (float*)w;  w += (size_t)N_NODES * HID * sizeof(float);
    float* t2p = (float*)w;  w += (size_t)N_NODES * 8 * sizeof(float);
    short* w1f = (short*)w;  w += (size_t)NWINT * 64 * 8 * sizeof(short);
    int* cnt   = (int*)w;    w += (size_t)8 * NBKT * sizeof(int);
    int* bkt   = (int*)w;    w += (size_t)8 * NBKT * BCAP2 * sizeof(int);

    (void)hipMemsetAsync(cnt, 0, (size_t)8 * NBKT * sizeof(int), stream);
    prep_w1_kernel<<<NWINT, 64, 0, stream>>>(W1, w1f);

    // gemm (8-row sequential strips) ++ fill interleaved 4:1
    fat1_kernel<<<GB1 + QBLK, 256, 0, stream>>>(x, w1f, t1, src, dst, cnt, bkt);

    agg1f_kernel<<<NBKT, 256, 0, stream>>>(t1, cnt, bkt, b1, W2, t2p);
    agg2_kernel<<<NBKT, 256, 0, stream>>>(t2p, cnt, bkt, b2, out);
}